// Round 4
// baseline (26329.794 us; speedup 1.0000x reference)
//
#include <hip/hip_runtime.h>
#include <hip/hip_fp16.h>
#include <stdint.h>

#define B_  512
#define S_  512
#define IN_ 118
#define H1_ 256
#define H2_ 128

typedef __attribute__((ext_vector_type(8))) short frag8;    // 8 fp16 = 4 VGPRs
typedef __attribute__((ext_vector_type(4))) float facc4;    // MFMA accumulator
typedef unsigned short u16;
typedef unsigned int   u32;

__device__ __forceinline__ void splitf(float v, u16& hi, u16& lo) {
    __half h = __float2half(v);          // RNE
    float hf = __half2float(h);
    __half l = __float2half(v - hf);
    hi = *(u16*)&h; lo = *(u16*)&l;
}
__device__ __forceinline__ float sigm_(float x) { return 1.f / (1.f + __expf(-x)); }
__device__ __forceinline__ float tanh_(float x) {
    float ax = fabsf(x);
    float e  = __expf(-2.f * ax);
    float r  = (1.f - e) / (1.f + e);
    return copysignf(r, x);
}

// ---------------- ws layout (bytes) ----------------
// 0        w1h  786432   fp16 [64 nt][12 kf][64 lane][8]
// 786432   w1l  786432
// 1572864  w2h  393216   fp16 [32 nt][12 kf][64 lane][8]
// 1966080  w2l  393216
// 2359296  c1s  524288   fp32 [512][256]
// 2883584  h1sH 262144   fp16 [512][256]
// 3145728  h1sL 262144
// 3407872  c2s  262144   fp32 [512][128]
// 3670016  h2sH 131072
// 3801088  h2sL 131072
// 3932160  ring u32 [2 parity][32 tile][Tc][16][256]  (packed lo<<16|hi)
// ---------------------------------------------------

__global__ void prep_weights(const float* __restrict__ Wf1, const float* __restrict__ Wi1,
                             const float* __restrict__ Wg1, const float* __restrict__ Wo1,
                             const float* __restrict__ Wf2, const float* __restrict__ Wi2,
                             const float* __restrict__ Wg2, const float* __restrict__ Wo2,
                             u16* __restrict__ w1h, u16* __restrict__ w1l,
                             u16* __restrict__ w2h, u16* __restrict__ w2l) {
    int idx = blockIdx.x * 256 + threadIdx.x;
    if (idx >= 589824) return;
    if (idx < 393216) {
        int j  = idx & 7;
        int L  = (idx >> 3) & 63;
        int fr = idx >> 9;            // nt*12 + kf
        int kf = fr % 12, nt = fr / 12;
        int khat = kf * 32 + (L >> 4) * 8 + j;   // B[k][n]: k = quad*8+j
        int n    = nt * 16 + (L & 15);           //          n = lane&15
        const float* Wg[4] = {Wf1, Wi1, Wg1, Wo1};
        float v = 0.f;
        if (khat < 128) {
            if (khat < IN_) v = Wg[n >> 8][(n & 255) * 374 + khat];      // x part
        } else {
            v = Wg[n >> 8][(n & 255) * 374 + (khat - 10)];               // h part
        }
        u16 hi, lo; splitf(v, hi, lo);
        w1h[idx] = hi; w1l[idx] = lo;
    } else {
        int i2 = idx - 393216;
        int j  = i2 & 7;
        int L  = (i2 >> 3) & 63;
        int fr = i2 >> 9;
        int kf = fr % 12, nt = fr / 12;
        int khat = kf * 32 + (L >> 4) * 8 + j;
        int n    = nt * 16 + (L & 15);
        const float* Wg[4] = {Wf2, Wi2, Wg2, Wo2};
        float v = Wg[n >> 7][(n & 127) * 384 + khat];
        u16 hi, lo; splitf(v, hi, lo);
        w2h[i2] = hi; w2l[i2] = lo;
    }
}

// Dynamic LDS (26624 B):
//  0      combH : u16 [16][392]   12544 B  (pitch 392: 16B-aligned, odd/16 kills bank conflicts)
//  12544  combL : u16 [16][392]   12544 B
//  25088  sS[16][8], sQ[16][8], sMu[16], sRs[16]  floats (1152 B)

__global__ __launch_bounds__(512, 1) void lstm_chunk(
    const float* __restrict__ x,
    const float* __restrict__ bf1, const float* __restrict__ bi1,
    const float* __restrict__ bg1, const float* __restrict__ bo1,
    const float* __restrict__ bf2, const float* __restrict__ bi2,
    const float* __restrict__ bg2, const float* __restrict__ bo2,
    const float* __restrict__ gamma1, const float* __restrict__ beta1,
    const float* __restrict__ gamma2, const float* __restrict__ beta2,
    const u16* __restrict__ w1h, const u16* __restrict__ w1l,
    const u16* __restrict__ w2h, const u16* __restrict__ w2l,
    u32* __restrict__ ring,
    float* __restrict__ c1s, u16* __restrict__ h1sH, u16* __restrict__ h1sL,
    float* __restrict__ c2s, u16* __restrict__ h2sH, u16* __restrict__ h2sL,
    int t0, int Tc, float* __restrict__ out)
{
    extern __shared__ char smem[];
    const int tid  = threadIdx.x;
    const int w    = tid >> 6;
    const int lane = tid & 63;
    const int q    = lane >> 4;
    const int cc   = lane & 15;
    const int bid  = blockIdx.x;

    u16*   combH = (u16*)smem;                    // [16][392]
    u16*   combL = (u16*)(smem + 12544);          // [16][392]
    float* sS    = (float*)(smem + 25088);        // [16][8]
    float* sQ    = sS + 128;
    float* sMu   = sQ + 128;
    float* sRs   = sMu + 16;

    if (bid < 32) {
        // ============ PHASE 1 : layer 1, chunk [t0, t0+Tc) ============
        if (t0 >= S_) return;
        const int tile = bid, b0 = tile * 16;

        frag8 wregH[8][3];   // hi weights, kf 0..2, resident
        #pragma unroll
        for (int k = 0; k < 8; ++k) {
            int nt = w + 8 * k;
            #pragma unroll
            for (int kf = 0; kf < 3; ++kf)
                wregH[k][kf] = *(const frag8*)&w1h[(((size_t)nt * 12 + kf) * 64 + lane) * 8];
        }
        float bz[8];
        #pragma unroll
        for (int k = 0; k < 8; ++k) {
            int n = (w + 8 * k) * 16 + cc;
            const float* bp = (n < 256) ? bf1 : (n < 512) ? bi1 : (n < 768) ? bg1 : bo1;
            bz[k] = bp[n & 255];
        }
        const int u0 = w * 16 + cc, u1 = u0 + 128;
        const float g0 = gamma1[u0], g1 = gamma1[u1];
        const float be0 = beta1[u0], be1 = beta1[u1];

        // state init: h-part of comb (cols 128..384) and c
        if (t0 == 0) {
            for (int i = tid; i < 4096; i += 512) {
                int row = i >> 8, col = i & 255;
                combH[row * 392 + 128 + col] = 0;
                combL[row * 392 + 128 + col] = 0;
            }
        } else {
            for (int i = tid; i < 4096; i += 512) {
                int row = i >> 8, col = i & 255;
                combH[row * 392 + 128 + col] = h1sH[(size_t)(b0 + row) * 256 + col];
                combL[row * 392 + 128 + col] = h1sL[(size_t)(b0 + row) * 256 + col];
            }
        }
        float cst[2][4];
        #pragma unroll
        for (int uu = 0; uu < 2; ++uu)
            #pragma unroll
            for (int r = 0; r < 4; ++r) {
                int m = q * 4 + r, u = (w + 8 * uu) * 16 + cc;
                cst[uu][r] = (t0 == 0) ? 0.f : c1s[(size_t)(b0 + m) * 256 + u];
            }
        __syncthreads();

        const int par = (t0 / Tc) & 1;
        u32* myring = ring + (((size_t)par * 32 + tile) * Tc) * 4096;

        for (int lt = 0; lt < Tc; ++lt) {
            const int t = t0 + lt;
            // stage x_t (split hi/lo) -> comb cols [0,128)
            for (int i = tid; i < 2048; i += 512) {
                int row = i >> 7, col = i & 127;
                float v = (col < IN_) ? x[((size_t)(b0 + row) * S_ + t) * IN_ + col] : 0.f;
                u16 hi, lo; splitf(v, hi, lo);
                combH[row * 392 + col] = hi;
                combL[row * 392 + col] = lo;
            }
            __syncthreads();

            facc4 acc[8];
            #pragma unroll
            for (int k = 0; k < 8; ++k) acc[k] = (facc4){0.f, 0.f, 0.f, 0.f};
            #pragma unroll
            for (int kf = 0; kf < 12; ++kf) {
                frag8 aH = *(frag8*)&combH[cc * 392 + kf * 32 + q * 8];
                frag8 aL = *(frag8*)&combL[cc * 392 + kf * 32 + q * 8];
                #pragma unroll
                for (int k = 0; k < 8; ++k) {
                    int nt = w + 8 * k;
                    frag8 bH = (kf < 3) ? wregH[k][kf]
                             : *(const frag8*)&w1h[(((size_t)nt * 12 + kf) * 64 + lane) * 8];
                    frag8 bL = *(const frag8*)&w1l[(((size_t)nt * 12 + kf) * 64 + lane) * 8];
                    acc[k] = __builtin_amdgcn_mfma_f32_16x16x32_f16(aH, bH, acc[k], 0, 0, 0);
                    acc[k] = __builtin_amdgcn_mfma_f32_16x16x32_f16(aL, bH, acc[k], 0, 0, 0);
                    acc[k] = __builtin_amdgcn_mfma_f32_16x16x32_f16(aH, bL, acc[k], 0, 0, 0);
                }
            }
            float hv[2][4];
            #pragma unroll
            for (int uu = 0; uu < 2; ++uu)
                #pragma unroll
                for (int r = 0; r < 4; ++r) {
                    float zf = acc[0 + uu][r] + bz[0 + uu];
                    float zi = acc[2 + uu][r] + bz[2 + uu];
                    float zg = acc[4 + uu][r] + bz[4 + uu];
                    float zo = acc[6 + uu][r] + bz[6 + uu];
                    float c  = sigm_(zf) * cst[uu][r] + sigm_(zi) * tanh_(zg);
                    cst[uu][r] = c;
                    hv[uu][r]  = sigm_(zo) * tanh_(c);
                }
            float s_[4], q_[4];
            #pragma unroll
            for (int r = 0; r < 4; ++r) {
                float a0 = hv[0][r], a1 = hv[1][r];
                s_[r] = a0 + a1;
                q_[r] = a0 * a0 + a1 * a1;
            }
            #pragma unroll
            for (int off = 1; off < 16; off <<= 1) {
                #pragma unroll
                for (int r = 0; r < 4; ++r) {
                    s_[r] += __shfl_xor(s_[r], off, 64);
                    q_[r] += __shfl_xor(q_[r], off, 64);
                }
            }
            if (cc == 0) {
                #pragma unroll
                for (int r = 0; r < 4; ++r) {
                    sS[(q * 4 + r) * 8 + w] = s_[r];
                    sQ[(q * 4 + r) * 8 + w] = q_[r];
                }
            }
            __syncthreads();
            if (tid < 16) {
                float ts = 0.f, tq = 0.f;
                #pragma unroll
                for (int k = 0; k < 8; ++k) { ts += sS[tid * 8 + k]; tq += sQ[tid * 8 + k]; }
                float mu  = ts * (1.f / H1_);
                float var = tq * (1.f / H1_) - mu * mu;
                sMu[tid] = mu;
                sRs[tid] = rsqrtf(var + 1e-5f);
            }
            __syncthreads();
            u32* slot = myring + (size_t)lt * 4096;
            #pragma unroll
            for (int uu = 0; uu < 2; ++uu) {
                float gg = uu ? g1 : g0, bb = uu ? be1 : be0;
                int u = (w + 8 * uu) * 16 + cc;
                #pragma unroll
                for (int r = 0; r < 4; ++r) {
                    int m = q * 4 + r;
                    float hn = (hv[uu][r] - sMu[m]) * sRs[m] * gg + bb;
                    u16 hi, lo; splitf(hn, hi, lo);
                    combH[m * 392 + 128 + u] = hi;
                    combL[m * 392 + 128 + u] = lo;
                    slot[m * 256 + u] = ((u32)lo << 16) | hi;
                }
            }
            __syncthreads();
        }
        // store carry state for next chunk
        #pragma unroll
        for (int uu = 0; uu < 2; ++uu)
            #pragma unroll
            for (int r = 0; r < 4; ++r) {
                int m = q * 4 + r, u = (w + 8 * uu) * 16 + cc;
                c1s[(size_t)(b0 + m) * 256 + u] = cst[uu][r];
            }
        for (int i = tid; i < 4096; i += 512) {
            int row = i >> 8, col = i & 255;
            h1sH[(size_t)(b0 + row) * 256 + col] = combH[row * 392 + 128 + col];
            h1sL[(size_t)(b0 + row) * 256 + col] = combL[row * 392 + 128 + col];
        }
    } else {
        // ============ PHASE 2 : layer 2, chunk [t2, t2+Tc) ============
        const int t2 = t0 - Tc;
        if (t2 < 0) return;
        const int tile = bid - 32, b0 = tile * 16;

        frag8 wregH2[4][6];   // hi weights, kf 0..5, resident
        #pragma unroll
        for (int k = 0; k < 4; ++k) {
            int nt = w + 8 * k;
            #pragma unroll
            for (int kf = 0; kf < 6; ++kf)
                wregH2[k][kf] = *(const frag8*)&w2h[(((size_t)nt * 12 + kf) * 64 + lane) * 8];
        }
        float bz[4];
        #pragma unroll
        for (int k = 0; k < 4; ++k) {
            int n = (w + 8 * k) * 16 + cc;
            const float* bp = (n < 128) ? bf2 : (n < 256) ? bi2 : (n < 384) ? bg2 : bo2;
            bz[k] = bp[n & 127];
        }
        const int u = w * 16 + cc;
        const float gg2 = gamma2[u], bb2 = beta2[u];

        if (t2 == 0) {
            for (int i = tid; i < 2048; i += 512) {
                int row = i >> 7, col = i & 127;
                combH[row * 392 + 256 + col] = 0;
                combL[row * 392 + 256 + col] = 0;
            }
        } else {
            for (int i = tid; i < 2048; i += 512) {
                int row = i >> 7, col = i & 127;
                combH[row * 392 + 256 + col] = h2sH[(size_t)(b0 + row) * 128 + col];
                combL[row * 392 + 256 + col] = h2sL[(size_t)(b0 + row) * 128 + col];
            }
        }
        float cst[4];
        #pragma unroll
        for (int r = 0; r < 4; ++r) {
            int m = q * 4 + r;
            cst[r] = (t2 == 0) ? 0.f : c2s[(size_t)(b0 + m) * 128 + u];
        }
        __syncthreads();

        const int par = (t2 / Tc) & 1;
        const u32* myring = ring + (((size_t)par * 32 + tile) * Tc) * 4096;

        for (int lt = 0; lt < Tc; ++lt) {
            const int t = t2 + lt;
            {   // ring slot (packed) -> comb cols [0,256)
                const u32* slot = myring + (size_t)lt * 4096;
                int row = tid >> 5, base = (tid & 31) * 8;
                #pragma unroll
                for (int j = 0; j < 8; ++j) {
                    u32 v = slot[row * 256 + base + j];
                    combH[row * 392 + base + j] = (u16)(v & 0xffffu);
                    combL[row * 392 + base + j] = (u16)(v >> 16);
                }
            }
            __syncthreads();

            facc4 acc[4];
            #pragma unroll
            for (int k = 0; k < 4; ++k) acc[k] = (facc4){0.f, 0.f, 0.f, 0.f};
            #pragma unroll
            for (int kf = 0; kf < 12; ++kf) {
                frag8 aH = *(frag8*)&combH[cc * 392 + kf * 32 + q * 8];
                frag8 aL = *(frag8*)&combL[cc * 392 + kf * 32 + q * 8];
                #pragma unroll
                for (int k = 0; k < 4; ++k) {
                    int nt = w + 8 * k;
                    frag8 bH = (kf < 6) ? wregH2[k][kf]
                             : *(const frag8*)&w2h[(((size_t)nt * 12 + kf) * 64 + lane) * 8];
                    frag8 bL = *(const frag8*)&w2l[(((size_t)nt * 12 + kf) * 64 + lane) * 8];
                    acc[k] = __builtin_amdgcn_mfma_f32_16x16x32_f16(aH, bH, acc[k], 0, 0, 0);
                    acc[k] = __builtin_amdgcn_mfma_f32_16x16x32_f16(aL, bH, acc[k], 0, 0, 0);
                    acc[k] = __builtin_amdgcn_mfma_f32_16x16x32_f16(aH, bL, acc[k], 0, 0, 0);
                }
            }
            float hv[4];
            #pragma unroll
            for (int r = 0; r < 4; ++r) {
                float zf = acc[0][r] + bz[0];
                float zi = acc[1][r] + bz[1];
                float zg = acc[2][r] + bz[2];
                float zo = acc[3][r] + bz[3];
                float c  = sigm_(zf) * cst[r] + sigm_(zi) * tanh_(zg);
                cst[r] = c;
                hv[r]  = sigm_(zo) * tanh_(c);
            }
            float s_[4], q_[4];
            #pragma unroll
            for (int r = 0; r < 4; ++r) { s_[r] = hv[r]; q_[r] = hv[r] * hv[r]; }
            #pragma unroll
            for (int off = 1; off < 16; off <<= 1) {
                #pragma unroll
                for (int r = 0; r < 4; ++r) {
                    s_[r] += __shfl_xor(s_[r], off, 64);
                    q_[r] += __shfl_xor(q_[r], off, 64);
                }
            }
            if (cc == 0) {
                #pragma unroll
                for (int r = 0; r < 4; ++r) {
                    sS[(q * 4 + r) * 8 + w] = s_[r];
                    sQ[(q * 4 + r) * 8 + w] = q_[r];
                }
            }
            __syncthreads();
            if (tid < 16) {
                float ts = 0.f, tq = 0.f;
                #pragma unroll
                for (int k = 0; k < 8; ++k) { ts += sS[tid * 8 + k]; tq += sQ[tid * 8 + k]; }
                float mu  = ts * (1.f / H2_);
                float var = tq * (1.f / H2_) - mu * mu;
                sMu[tid] = mu;
                sRs[tid] = rsqrtf(var + 1e-5f);
            }
            __syncthreads();
            #pragma unroll
            for (int r = 0; r < 4; ++r) {
                int m = q * 4 + r;
                float hn = (hv[r] - sMu[m]) * sRs[m] * gg2 + bb2;
                u16 hi, lo; splitf(hn, hi, lo);
                combH[m * 392 + 256 + u] = hi;
                combL[m * 392 + 256 + u] = lo;
                if (t == S_ - 1) out[(size_t)(b0 + m) * H2_ + u] = hn;
            }
            __syncthreads();
        }
        #pragma unroll
        for (int r = 0; r < 4; ++r) {
            int m = q * 4 + r;
            c2s[(size_t)(b0 + m) * 128 + u] = cst[r];
        }
        for (int i = tid; i < 2048; i += 512) {
            int row = i >> 7, col = i & 127;
            h2sH[(size_t)(b0 + row) * 128 + col] = combH[row * 392 + 256 + col];
            h2sL[(size_t)(b0 + row) * 128 + col] = combL[row * 392 + 256 + col];
        }
    }
}

extern "C" void kernel_launch(void* const* d_in, const int* in_sizes, int n_in,
                              void* d_out, int out_size, void* d_ws, size_t ws_size,
                              hipStream_t stream) {
    const float* x      = (const float*)d_in[0];
    const float* Wf1    = (const float*)d_in[1];
    const float* Wi1    = (const float*)d_in[2];
    const float* Wg1    = (const float*)d_in[3];
    const float* Wo1    = (const float*)d_in[4];
    const float* bf1    = (const float*)d_in[5];
    const float* bi1    = (const float*)d_in[6];
    const float* bg1    = (const float*)d_in[7];
    const float* bo1    = (const float*)d_in[8];
    const float* Wf2    = (const float*)d_in[9];
    const float* Wi2    = (const float*)d_in[10];
    const float* Wg2    = (const float*)d_in[11];
    const float* Wo2    = (const float*)d_in[12];
    const float* bf2    = (const float*)d_in[13];
    const float* bi2    = (const float*)d_in[14];
    const float* bg2    = (const float*)d_in[15];
    const float* bo2    = (const float*)d_in[16];
    const float* gamma1 = (const float*)d_in[17];
    const float* beta1  = (const float*)d_in[18];
    const float* gamma2 = (const float*)d_in[19];
    const float* beta2  = (const float*)d_in[20];

    char* ws = (char*)d_ws;
    u16*   w1h  = (u16*)ws;
    u16*   w1l  = (u16*)(ws + 786432);
    u16*   w2h  = (u16*)(ws + 1572864);
    u16*   w2l  = (u16*)(ws + 1966080);
    float* c1s  = (float*)(ws + 2359296);
    u16*   h1sH = (u16*)(ws + 2883584);
    u16*   h1sL = (u16*)(ws + 3145728);
    float* c2s  = (float*)(ws + 3407872);
    u16*   h2sH = (u16*)(ws + 3670016);
    u16*   h2sL = (u16*)(ws + 3801088);
    u32*   ring = (u32*)(ws + 3932160);

    // chunk length: largest Tc whose double-buffered ring fits the workspace
    int Tc = 2;
    const int cands[6] = {64, 32, 16, 8, 4, 2};
    for (int i = 0; i < 6; ++i) {
        size_t need = 3932160 + (size_t)2 * 32 * cands[i] * 16384;
        if (need <= ws_size) { Tc = cands[i]; break; }
    }
    const int nch = S_ / Tc;

    prep_weights<<<2304, 256, 0, stream>>>(Wf1, Wi1, Wg1, Wo1, Wf2, Wi2, Wg2, Wo2,
                                           w1h, w1l, w2h, w2l);

    // dispatch k: blocks 0..31 run layer-1 chunk k; blocks 32..63 run layer-2 chunk k-1.
    // Layer-2 reads ring data written by the PREVIOUS dispatch (parity double-buffer) —
    // cross-dispatch coherence is guaranteed on a stream; zero in-kernel cross-block sync.
    for (int k = 0; k <= nch; ++k) {
        lstm_chunk<<<64, 512, 26624, stream>>>(
            x, bf1, bi1, bg1, bo1, bf2, bi2, bg2, bo2,
            gamma1, beta1, gamma2, beta2,
            w1h, w1l, w2h, w2l, ring,
            c1s, h1sH, h1sL, c2s, h2sH, h2sL,
            k * Tc, Tc, (float*)d_out);
    }
}